// Round 2
// 1075.275 us; speedup vs baseline: 1.0159x; 1.0159x over previous
//
#include <hip/hip_runtime.h>
#include <hip/hip_bf16.h>
#include <math.h>

typedef __attribute__((ext_vector_type(8))) short  short8;
typedef __attribute__((ext_vector_type(4))) float  floatx4;

#define D      1024
#define H1     32
#define H2     8
#define NTILE  20000
#define BATCH  8
#define ROWS   128          // rows per block (1250 blocks)
#define HS     33           // padded LDS row stride for h1

// ---------------------------------------------------------------------------
// fp32 -> bf16 hi/lo split (truncation; hi+lo captures fp32 to ~2^-16 rel)
// ---------------------------------------------------------------------------
__device__ __forceinline__ void split8(const float4 a, const float4 b,
                                       short8& hi, short8& lo)
{
    float f[8] = {a.x, a.y, a.z, a.w, b.x, b.y, b.z, b.w};
    #pragma unroll
    for (int j = 0; j < 8; ++j) {
        unsigned u = __float_as_uint(f[j]);
        unsigned short h = (unsigned short)(u >> 16);
        float hf = __uint_as_float(((unsigned)h) << 16);
        float l  = f[j] - hf;                      // exact
        hi[j] = (short)h;
        lo[j] = (short)(__float_as_uint(l) >> 16);
    }
}

// ---------------------------------------------------------------------------
// Kernel 0: pre-split W1 (32x1024 fp32) into bf16 hi/lo arrays in ws
// ---------------------------------------------------------------------------
__global__ void w1_split(const float* __restrict__ W1,
                         unsigned short* __restrict__ whi,
                         unsigned short* __restrict__ wlo)
{
    const int i = blockIdx.x * 256 + threadIdx.x;   // 32768 elems, 128 blocks
    const float f = W1[i];
    const unsigned u = __float_as_uint(f);
    const unsigned short h = (unsigned short)(u >> 16);
    const float l = f - __uint_as_float(((unsigned)h) << 16);
    whi[i] = h;
    wlo[i] = (unsigned short)(__float_as_uint(l) >> 16);
}

// ---------------------------------------------------------------------------
// Kernel 1: streaming MFMA MLP.  Layer 1 via split-bf16 16x16x32 MFMA.
// Fully software-pipelined K-loop: ALL 8 fragment loads (A rows from HBM and
// W1 hi/lo fragments from L1/L2) for step s+1 are issued before step s's
// MFMAs, in ping-pong register buffers.  This keeps the vmcnt wait for step s
// counted (8 younger loads stay in flight) instead of draining the A-prefetch
// that the old same-step B-load forced (vmcnt(3) -> effective prefetch ~100cy
// vs ~900cy HBM latency).  Arithmetic order identical -> bit-identical output.
// ---------------------------------------------------------------------------
#define LOADSTEP(Bh0v,Bh1v,Bl0v,Bl1v, Aa0,Ab0,Aa1,Ab1, kk)                      \
{                                                                               \
    Bh0v = *(const short8*)(bh0 + (kk));                                        \
    Bh1v = *(const short8*)(bh1 + (kk));                                        \
    Bl0v = *(const short8*)(bl0 + (kk));                                        \
    Bl1v = *(const short8*)(bl1 + (kk));                                        \
    Aa0  = *(const float4*)(xr0 + (kk));                                        \
    Ab0  = *(const float4*)(xr0 + (kk) + 4);                                    \
    Aa1  = *(const float4*)(xr1 + (kk));                                        \
    Ab1  = *(const float4*)(xr1 + (kk) + 4);                                    \
}

#define COMPSTEP(Bh0v,Bh1v,Bl0v,Bl1v, Aa0,Ab0,Aa1,Ab1)                          \
{                                                                               \
    short8 ah, al;                                                              \
    split8(Aa0, Ab0, ah, al);                                                   \
    acc[0][0] = __builtin_amdgcn_mfma_f32_16x16x32_bf16(ah, Bh0v, acc[0][0], 0,0,0);\
    acc[0][0] = __builtin_amdgcn_mfma_f32_16x16x32_bf16(al, Bh0v, acc[0][0], 0,0,0);\
    acc[0][0] = __builtin_amdgcn_mfma_f32_16x16x32_bf16(ah, Bl0v, acc[0][0], 0,0,0);\
    acc[0][1] = __builtin_amdgcn_mfma_f32_16x16x32_bf16(ah, Bh1v, acc[0][1], 0,0,0);\
    acc[0][1] = __builtin_amdgcn_mfma_f32_16x16x32_bf16(al, Bh1v, acc[0][1], 0,0,0);\
    acc[0][1] = __builtin_amdgcn_mfma_f32_16x16x32_bf16(ah, Bl1v, acc[0][1], 0,0,0);\
    split8(Aa1, Ab1, ah, al);                                                   \
    acc[1][0] = __builtin_amdgcn_mfma_f32_16x16x32_bf16(ah, Bh0v, acc[1][0], 0,0,0);\
    acc[1][0] = __builtin_amdgcn_mfma_f32_16x16x32_bf16(al, Bh0v, acc[1][0], 0,0,0);\
    acc[1][0] = __builtin_amdgcn_mfma_f32_16x16x32_bf16(ah, Bl0v, acc[1][0], 0,0,0);\
    acc[1][1] = __builtin_amdgcn_mfma_f32_16x16x32_bf16(ah, Bh1v, acc[1][1], 0,0,0);\
    acc[1][1] = __builtin_amdgcn_mfma_f32_16x16x32_bf16(al, Bh1v, acc[1][1], 0,0,0);\
    acc[1][1] = __builtin_amdgcn_mfma_f32_16x16x32_bf16(ah, Bl1v, acc[1][1], 0,0,0);\
}

__global__ __launch_bounds__(256, 3)
void mlp_mfma(const float* __restrict__ x,
              const unsigned short* __restrict__ whi, const unsigned short* __restrict__ wlo,
              const float* __restrict__ b1,
              const float* __restrict__ W2, const float* __restrict__ b2,
              const float* __restrict__ W3, const float* __restrict__ b3,
              const float* __restrict__ Wsc, const float* __restrict__ bsc,
              float* __restrict__ outbuf, float* __restrict__ scores)
{
    __shared__ float hls[ROWS * HS];
    __shared__ float W2s[H2 * H1], W3s[H1 * H2], Wscs[H1], b2s[H2], b3s[H1];
    __shared__ float bscs;

    const int t = threadIdx.x;
    if (t < H2 * H1) W2s[t] = W2[t];
    if (t < H1 * H2) W3s[t] = W3[t];
    if (t < H1) { Wscs[t] = Wsc[t]; b3s[t] = b3[t]; }
    if (t < H2) b2s[t] = b2[t];
    if (t == 0) bscs = bsc[0];

    const int wave = t >> 6, lane = t & 63, quad = lane >> 4, l15 = lane & 15;
    const long row0 = (long)blockIdx.x * ROWS;

    // A fragment pointers (M-tiles 0/1 of this wave), already offset by quad*8
    const float* xr0 = x + (row0 + wave * 32 + l15) * D + quad * 8;
    const float* xr1 = xr0 + 16 * D;
    // B fragment pointers (N-tiles 0/1), lane holds W1[ch][k0+quad*8 .. +7]
    const unsigned short* bh0 = whi + l15 * D + quad * 8;
    const unsigned short* bh1 = whi + (16 + l15) * D + quad * 8;
    const unsigned short* bl0 = wlo + l15 * D + quad * 8;
    const unsigned short* bl1 = wlo + (16 + l15) * D + quad * 8;

    floatx4 acc[2][2] = {};

    // ping-pong fragment buffers (all compile-time indexed -> registers)
    short8 B0h0, B0h1, B0l0, B0l1, B1h0, B1h1, B1l0, B1l1;
    float4 A00a, A00b, A01a, A01b, A10a, A10b, A11a, A11b;

    // prologue: step 0 into buffer 0
    LOADSTEP(B0h0,B0h1,B0l0,B0l1, A00a,A00b,A01a,A01b, 0);

    // 32 K-steps of 32 columns each, unrolled in pairs for register rotation.
    // Loads for step s+1 are always issued BEFORE the MFMAs of step s.
    #pragma unroll
    for (int it = 0; it < 16; ++it) {
        const int k1 = (2 * it + 1) * 32;
        const int k2 = (2 * it + 2) * 32;
        LOADSTEP(B1h0,B1h1,B1l0,B1l1, A10a,A10b,A11a,A11b, k1);
        COMPSTEP(B0h0,B0h1,B0l0,B0l1, A00a,A00b,A01a,A01b);
        if (it < 15) {
            LOADSTEP(B0h0,B0h1,B0l0,B0l1, A00a,A00b,A01a,A01b, k2);
        }
        COMPSTEP(B1h0,B1h1,B1l0,B1l1, A10a,A10b,A11a,A11b);
    }

    // epilogue: h1 = relu(acc + b1) -> LDS (padded stride, conflict-light)
    const float b1c0 = b1[l15], b1c1 = b1[16 + l15];
    const int rbase = wave * 32 + quad * 4;
    #pragma unroll
    for (int mt = 0; mt < 2; ++mt)
        #pragma unroll
        for (int r = 0; r < 4; ++r) {
            const int row = rbase + mt * 16 + r;
            hls[row * HS + l15]      = fmaxf(acc[mt][0][r] + b1c0, 0.f);
            hls[row * HS + 16 + l15] = fmaxf(acc[mt][1][r] + b1c1, 0.f);
        }
    __syncthreads();

    // per-tile tail: layer2(32->8), layer3(8->32, in place), score
    if (t < ROWS) {
        float h[H1];
        #pragma unroll
        for (int i = 0; i < H1; ++i) h[i] = hls[t * HS + i];
        float h2[H2];
        #pragma unroll
        for (int g = 0; g < H2; ++g) {
            float s = b2s[g];
            #pragma unroll
            for (int hh = 0; hh < H1; ++hh) s = fmaf(W2s[g * H1 + hh], h[hh], s);
            h2[g] = fmaxf(s, 0.f);
        }
        float sacc = bscs;
        #pragma unroll
        for (int hh = 0; hh < H1; ++hh) {
            float s = b3s[hh];
            #pragma unroll
            for (int g = 0; g < H2; ++g) s = fmaf(W3s[hh * H2 + g], h2[g], s);
            s = fmaxf(s, 0.f);
            hls[t * HS + hh] = s;          // in place: row owned by this thread
            sacc = fmaf(Wscs[hh], s, sacc);
        }
        scores[row0 + t] = fmaxf(sacc, 0.f);
    }
    __syncthreads();

    // cooperative coalesced store of the out-tile (128 rows x 32 ch)
    const long obase = row0 * H1;
    #pragma unroll
    for (int i = t; i < ROWS * H1; i += 256) {
        const int r = i >> 5, c = i & 31;
        outbuf[obase + i] = hls[r * HS + c];
    }
}

// ---------------------------------------------------------------------------
// Kernel 2: per batch: stable bottom-10/top-10 via u64 keys, features,
// 692->32->32->1 classifier.  (unchanged — verified bit-exact)
// ---------------------------------------------------------------------------
__global__ __launch_bounds__(256)
void select_classify(const float* __restrict__ scores, const float* __restrict__ outbuf,
                     const float* __restrict__ Wc1, const float* __restrict__ bc1,
                     const float* __restrict__ Wc2, const float* __restrict__ bc2,
                     const float* __restrict__ Wc3, const float* __restrict__ bc3,
                     float* __restrict__ y)
{
    typedef unsigned long long u64;
    const int b = blockIdx.x, t = threadIdx.x;
    const float* sc = scores + (long)b * NTILE;

    u64 top[10], bot[10];
    #pragma unroll
    for (int j = 0; j < 10; ++j) { top[j] = 0ULL; bot[j] = ~0ULL; }

    for (int i = t; i < NTILE; i += 256) {
        const u64 key = ((u64)__float_as_uint(sc[i]) << 32) | (unsigned)i;
        if (key > top[9]) {
            int p = 9;
            while (p > 0 && key > top[p - 1]) { top[p] = top[p - 1]; --p; }
            top[p] = key;
        }
        if (key < bot[9]) {
            int p = 9;
            while (p > 0 && key < bot[p - 1]) { bot[p] = bot[p - 1]; --p; }
            bot[p] = key;
        }
    }

    __shared__ u64 LT[256][10], LB[256][10];
    #pragma unroll
    for (int j = 0; j < 10; ++j) { LT[t][j] = top[j]; LB[t][j] = bot[j]; }
    __syncthreads();

    for (int stride = 128; stride >= 1; stride >>= 1) {
        if (t < stride) {
            u64 a[10], m[10];
            #pragma unroll
            for (int j = 0; j < 10; ++j) a[j] = LT[t + stride][j];
            int i1 = 0, i2 = 0;
            #pragma unroll
            for (int k = 0; k < 10; ++k) m[k] = (top[i1] >= a[i2]) ? top[i1++] : a[i2++];
            #pragma unroll
            for (int k = 0; k < 10; ++k) { top[k] = m[k]; LT[t][k] = m[k]; }
            #pragma unroll
            for (int j = 0; j < 10; ++j) a[j] = LB[t + stride][j];
            i1 = 0; i2 = 0;
            #pragma unroll
            for (int k = 0; k < 10; ++k) m[k] = (bot[i1] <= a[i2]) ? bot[i1++] : a[i2++];
            #pragma unroll
            for (int k = 0; k < 10; ++k) { bot[k] = m[k]; LB[t][k] = m[k]; }
        }
        __syncthreads();
    }

    __shared__ int   selIdx[20];
    __shared__ float selSc[20];
    if (t == 0) {
        for (int j = 0; j < 10; ++j) {
            selIdx[j]      = (int)(bot[j] & 0xffffffffULL);
            selSc[j]       = __uint_as_float((unsigned)(bot[j] >> 32));
            selIdx[19 - j] = (int)(top[j] & 0xffffffffULL);
            selSc[19 - j]  = __uint_as_float((unsigned)(top[j] >> 32));
        }
    }
    __syncthreads();

    __shared__ float feat[692];
    if (t < 20) feat[t] = selSc[t];
    for (int idx = t; idx < 640; idx += 256) {
        const int j = idx >> 5, c = idx & 31;
        feat[52 + c * 20 + j] = outbuf[((long)b * NTILE + selIdx[j]) * H1 + c];
    }
    __syncthreads();
    if (t < 32) {
        float s = 0.f;
        for (int j = 0; j < 20; ++j) s += feat[52 + t * 20 + j];
        feat[20 + t] = s * (1.0f / 20.0f);
    }
    __syncthreads();

    __shared__ float z1s[32], z2s[32];
    if (t < 32) {
        float s = bc1[t];
        for (int k = 0; k < 692; ++k) s = fmaf(Wc1[t * 692 + k], feat[k], s);
        z1s[t] = fmaxf(s, 0.f);
    }
    __syncthreads();
    if (t < 32) {
        float s = bc2[t];
        #pragma unroll
        for (int k = 0; k < 32; ++k) s = fmaf(Wc2[t * 32 + k], z1s[k], s);
        z2s[t] = fmaxf(s, 0.f);
    }
    __syncthreads();
    if (t == 0) {
        float s = bc3[0];
        #pragma unroll
        for (int k = 0; k < 32; ++k) s = fmaf(Wc3[k], z2s[k], s);
        y[b] = 1.f / (1.f + expf(-s));
    }
}

// ---------------------------------------------------------------------------
extern "C" void kernel_launch(void* const* d_in, const int* in_sizes, int n_in,
                              void* d_out, int out_size, void* d_ws, size_t ws_size,
                              hipStream_t stream)
{
    const float* x   = (const float*)d_in[0];
    const float* W1  = (const float*)d_in[1];
    const float* b1  = (const float*)d_in[2];
    const float* W2  = (const float*)d_in[3];
    const float* b2  = (const float*)d_in[4];
    const float* W3  = (const float*)d_in[5];
    const float* b3  = (const float*)d_in[6];
    const float* Wsc = (const float*)d_in[7];
    const float* bsc = (const float*)d_in[8];
    const float* Wc1 = (const float*)d_in[9];
    const float* bc1 = (const float*)d_in[10];
    const float* Wc2 = (const float*)d_in[11];
    const float* bc2 = (const float*)d_in[12];
    const float* Wc3 = (const float*)d_in[13];
    const float* bc3 = (const float*)d_in[14];
    float* yout = (float*)d_out;

    float* scores = (float*)d_ws;                              // 160000 f
    float* outbuf = scores + (size_t)BATCH * NTILE;            // 5.12M f
    unsigned short* whi = (unsigned short*)(outbuf + (size_t)BATCH * NTILE * H1);
    unsigned short* wlo = whi + (size_t)H1 * D;

    w1_split<<<(H1 * D) / 256, 256, 0, stream>>>(W1, whi, wlo);

    dim3 grid1((BATCH * NTILE) / ROWS);   // 1250 blocks
    mlp_mfma<<<grid1, 256, 0, stream>>>(x, whi, wlo, b1, W2, b2, W3, b3,
                                        Wsc, bsc, outbuf, scores);
    select_classify<<<BATCH, 256, 0, stream>>>(scores, outbuf,
                                               Wc1, bc1, Wc2, bc2, Wc3, bc3, yout);
}